// Round 7
// baseline (222.365 us; speedup 1.0000x reference)
//
#include <hip/hip_runtime.h>
#include <cstdint>
#include <cstddef>

// ---------------------------------------------------------------------------
// Mamba2 layer forward (B=4, L=2048, d_model=512, d_inner=1024, d_state=128,
// nheads=1, d_conv=4). SSD formulation: scan as chunked bf16 MFMA GEMMs.
// R5 SSD 609->281; R6 global_load_lds; R7 XOR-swizzle; R8 fusion ->233;
// R10 XCD swizzle; R11 conv_tr odd-bank tile ->219; R12 wave-per-row
// gate_norm ->214. R13 GEMM2 64x128 retile ->206. R14 gate fusion regressed
// at low occupancy. R15/16 gemm_y retile ->202.8. R17 gemm1 64x128 ->193.6.
// R18 occupancy audit (64x64 everywhere) ->190.2. R19 gate+RMSNorm fusion
// re-applied at high occupancy (7 launches) ->186.3.
// R20: VGPR-cap experiment. R1 counters showed gemm_y at VGPR=76 -> ~5-6
// waves/SIMD while 16KB LDS permits 8+. __launch_bounds__(256,8) on the
// 64x64 GEMM bodies (gemmA/gemm_y/gemm2) targets VGPR<=64 = 8 blocks/CU;
// (256,6) on gemm1/conv_tr matches their LDS caps. No structural change.
// ---------------------------------------------------------------------------

typedef __bf16 bf16_t;
typedef __bf16 bf16x8 __attribute__((ext_vector_type(8)));
typedef __bf16 bf16x4 __attribute__((ext_vector_type(4)));
typedef __bf16 bf16x2 __attribute__((ext_vector_type(2)));
typedef float  f32x4  __attribute__((ext_vector_type(4)));

#define BATCH   4
#define SEQLEN  2048
#define MROWS   8192
#define DMODEL  512
#define DINNER  1024
#define DSTATE  128
#define NZX     2304
#define NCONV   1280
#define CHUNK   128
#define NCHUNK  16
#define NBC     64            // BATCH * NCHUNK

__device__ __forceinline__ float siluf(float x) { return x / (1.f + __expf(-x)); }

// async global->LDS, 16B per lane. LDS dst is wave-uniform base + lane*16.
__device__ __forceinline__ void load_lds16(const bf16_t* g, bf16_t* l)
{
    __builtin_amdgcn_global_load_lds(
        (const __attribute__((address_space(1))) void*)g,
        (__attribute__((address_space(3))) void*)l,
        16, 0, 0);
}

// ---------------------------------------------------------------------------
// 64x128-tile GEMM body (smem 24 KB): BK=64, XOR-swizzled global_load_lds
// staging, per-wave 32x64 (acc[2][4]), 4 waves = 2M x 2N.
// ---------------------------------------------------------------------------
template <typename OutT>
__device__ __forceinline__ void gemm64_body(
    unsigned char* smem,
    const bf16_t* __restrict__ A, const bf16_t* __restrict__ B,
    OutT* __restrict__ C, int Ntot, int K, int lda, int ldb, int bn, int bm)
{
    bf16_t* As = (bf16_t*)smem;            // 64 x 64  =  8 KB
    bf16_t* Bs = (bf16_t*)(smem + 8192);   // 128 x 64 = 16 KB

    const int tid  = threadIdx.x;
    const int wave = tid >> 6, lane = tid & 63;
    const int lr = lane & 15, q = lane >> 4;
    const int wm = (wave & 1) * 32, wn = (wave >> 1) * 64;

    f32x4 acc[2][4];
    #pragma unroll
    for (int i = 0; i < 2; ++i)
        #pragma unroll
        for (int j = 0; j < 4; ++j)
            acc[i][j] = (f32x4){0.f, 0.f, 0.f, 0.f};

    const int row_a0 = bm * 64, row_b0 = bn * 128;
    const int srow = tid >> 3;
    const int gsw  = (((tid & 7) ^ (srow & 7))) * 8;
    const int lsl  = (tid & 7) * 8;

    for (int kt = 0; kt < K; kt += 64) {
        #pragma unroll
        for (int i = 0; i < 2; ++i) {
            int row = srow + i * 32;
            load_lds16(&A[(size_t)(row_a0 + row) * lda + kt + gsw], &As[row * 64 + lsl]);
        }
        #pragma unroll
        for (int i = 0; i < 4; ++i) {
            int row = srow + i * 32;
            load_lds16(&B[(size_t)(row_b0 + row) * ldb + kt + gsw], &Bs[row * 64 + lsl]);
        }
        __syncthreads();
        #pragma unroll
        for (int k0 = 0; k0 < 64; k0 += 32) {
            bf16x8 af[2], bfr[4];
            #pragma unroll
            for (int mi = 0; mi < 2; ++mi) {
                int r = wm + mi * 16 + lr, kc = (k0 >> 3) + q;
                af[mi] = *reinterpret_cast<const bf16x8*>(
                    &As[r * 64 + ((kc ^ (r & 7)) << 3)]);
            }
            #pragma unroll
            for (int ni = 0; ni < 4; ++ni) {
                int r = wn + ni * 16 + lr, kc = (k0 >> 3) + q;
                bfr[ni] = *reinterpret_cast<const bf16x8*>(
                    &Bs[r * 64 + ((kc ^ (r & 7)) << 3)]);
            }
            #pragma unroll
            for (int mi = 0; mi < 2; ++mi)
                #pragma unroll
                for (int ni = 0; ni < 4; ++ni)
                    acc[mi][ni] = __builtin_amdgcn_mfma_f32_16x16x32_bf16(
                        af[mi], bfr[ni], acc[mi][ni], 0, 0, 0);
        }
        __syncthreads();
    }

    #pragma unroll
    for (int mi = 0; mi < 2; ++mi)
        #pragma unroll
        for (int ni = 0; ni < 4; ++ni)
            #pragma unroll
            for (int ri = 0; ri < 4; ++ri) {
                int row = row_a0 + wm + mi * 16 + q * 4 + ri;
                int col = row_b0 + wn + ni * 16 + lr;
                C[(size_t)row * Ntot + col] = (OutT)acc[mi][ni][ri];
            }
}

// ---------------------------------------------------------------------------
// 64x64-tile GEMM body (smem 16 KB): BK=64, per-wave 32x32 (acc[2][2]),
// 4 waves = 2M x 2N. Same staging/swizzle/accumulation order as gemm64_body.
// ---------------------------------------------------------------------------
template <typename OutT>
__device__ __forceinline__ void gemm6464_body(
    unsigned char* smem,
    const bf16_t* __restrict__ A, const bf16_t* __restrict__ B,
    OutT* __restrict__ C, int Ntot, int K, int lda, int ldb, int bn, int bm)
{
    bf16_t* As = (bf16_t*)smem;            // 64 x 64 = 8 KB
    bf16_t* Bs = (bf16_t*)(smem + 8192);   // 64 x 64 = 8 KB

    const int tid  = threadIdx.x;
    const int wave = tid >> 6, lane = tid & 63;
    const int lr = lane & 15, q = lane >> 4;
    const int wm = (wave & 1) * 32, wn = (wave >> 1) * 32;

    f32x4 acc[2][2];
    #pragma unroll
    for (int i = 0; i < 2; ++i)
        #pragma unroll
        for (int j = 0; j < 2; ++j)
            acc[i][j] = (f32x4){0.f, 0.f, 0.f, 0.f};

    const int row_a0 = bm * 64, row_b0 = bn * 64;
    const int srow = tid >> 3;
    const int gsw  = (((tid & 7) ^ (srow & 7))) * 8;
    const int lsl  = (tid & 7) * 8;

    for (int kt = 0; kt < K; kt += 64) {
        #pragma unroll
        for (int i = 0; i < 2; ++i) {
            int row = srow + i * 32;
            load_lds16(&A[(size_t)(row_a0 + row) * lda + kt + gsw], &As[row * 64 + lsl]);
            load_lds16(&B[(size_t)(row_b0 + row) * ldb + kt + gsw], &Bs[row * 64 + lsl]);
        }
        __syncthreads();
        #pragma unroll
        for (int k0 = 0; k0 < 64; k0 += 32) {
            bf16x8 af[2], bfr[2];
            #pragma unroll
            for (int mi = 0; mi < 2; ++mi) {
                int r = wm + mi * 16 + lr, kc = (k0 >> 3) + q;
                af[mi] = *reinterpret_cast<const bf16x8*>(
                    &As[r * 64 + ((kc ^ (r & 7)) << 3)]);
            }
            #pragma unroll
            for (int ni = 0; ni < 2; ++ni) {
                int r = wn + ni * 16 + lr, kc = (k0 >> 3) + q;
                bfr[ni] = *reinterpret_cast<const bf16x8*>(
                    &Bs[r * 64 + ((kc ^ (r & 7)) << 3)]);
            }
            #pragma unroll
            for (int mi = 0; mi < 2; ++mi)
                #pragma unroll
                for (int ni = 0; ni < 2; ++ni)
                    acc[mi][ni] = __builtin_amdgcn_mfma_f32_16x16x32_bf16(
                        af[mi], bfr[ni], acc[mi][ni], 0, 0, 0);
        }
        __syncthreads();
    }

    #pragma unroll
    for (int mi = 0; mi < 2; ++mi)
        #pragma unroll
        for (int ni = 0; ni < 2; ++ni)
            #pragma unroll
            for (int ri = 0; ri < 4; ++ri) {
                int row = row_a0 + wm + mi * 16 + q * 4 + ri;
                int col = row_b0 + wn + ni * 16 + lr;
                C[(size_t)row * Ntot + col] = (OutT)acc[mi][ni][ri];
            }
}

// ---------------------------------------------------------------------------
// cumsum body (per chunk bc, active threads 0..127): decay scalars.
// ---------------------------------------------------------------------------
__device__ __forceinline__ void cumsum_body(
    const float* __restrict__ dtv, const float* __restrict__ A_log,
    float* __restrict__ sarr, float* __restrict__ Pv,
    float* __restrict__ EdTv, float* __restrict__ chp, int bc)
{
    __shared__ float w0sum, stot;
    int j = threadIdx.x;
    bool active = j < CHUNK;
    int lane = j & 63;
    int r = bc * CHUNK + j;
    float A = -expf(A_log[0]);
    float dt = active ? dtv[r] : 0.f;
    float s = dt;
    #pragma unroll
    for (int m = 1; m <= 32; m <<= 1) {
        float o = __shfl_up(s, m);
        if (lane >= m) s += o;
    }
    if (j == 63) w0sum = s;
    __syncthreads();
    if (j >= 64 && active) s += w0sum;
    if (j == 127) stot = s;
    __syncthreads();
    if (active) {
        float sT = stot;
        sarr[r] = s;
        Pv[r]   = expf(A * s);
        EdTv[r] = expf(A * (sT - s)) * dt;
        if (j == 127) chp[bc] = expf(A * sT);
    }
}

// GEMM1 (64x128 tiles, 2304 blocks, XCD bm bands) + cumsum tail blocks
__global__ __launch_bounds__(256, 6) void gemm1_kernel(
    const bf16_t* __restrict__ xb, const bf16_t* __restrict__ winb,
    bf16_t* __restrict__ zx, const float* __restrict__ dtv,
    const float* __restrict__ A_log, float* __restrict__ sarr,
    float* __restrict__ Pv, float* __restrict__ EdTv, float* __restrict__ chp)
{
    __shared__ __align__(16) unsigned char smem[24576];
    int linear = blockIdx.x;
    if (linear < (NZX / 128) * (MROWS / 64)) {      // 18*128 = 2304
        int xcd = linear & 7, j = linear >> 3;      // j in [0,288)
        int bm = xcd * 16 + (j & 15);               // 16-row-tile band per XCD
        int bn = j >> 4;                            // [0,18)
        gemm64_body<bf16_t>(smem, xb, winb, zx, NZX, DMODEL, DMODEL, DMODEL, bn, bm);
    } else {
        cumsum_body(dtv, A_log, sarr, Pv, EdTv, chp, linear - 2304);
    }
}

// ---------------------------------------------------------------------------
// GEMM2: 64x64 tiles, 1024 blocks, XCD bands; out = (yb @ woutb^T)
// * rsqrt(ss/1024 + eps) per row. woutb carries norm_w (folded at cast).
// ---------------------------------------------------------------------------
__global__ __launch_bounds__(256, 8) void gemm2_kernel(
    const bf16_t* __restrict__ yb, const bf16_t* __restrict__ woutb,
    const float* __restrict__ ss, float* __restrict__ out)
{
    __shared__ __align__(16) bf16_t As[64 * 64];
    __shared__ __align__(16) bf16_t Bs[64 * 64];

    int id  = blockIdx.x;              // [0,1024)
    int xcd = id & 7, j = id >> 3;     // j in [0,128)
    int bm  = xcd * 16 + (j & 15);     // [0,128)
    int bn  = j >> 4;                  // [0,8)

    const int tid  = threadIdx.x;
    const int wave = tid >> 6, lane = tid & 63;
    const int lr = lane & 15, q = lane >> 4;
    const int wm = (wave & 1) * 32, wn = (wave >> 1) * 32;

    f32x4 acc[2][2];
    #pragma unroll
    for (int i = 0; i < 2; ++i)
        #pragma unroll
        for (int jj = 0; jj < 2; ++jj)
            acc[i][jj] = (f32x4){0.f, 0.f, 0.f, 0.f};

    const int row_a0 = bm * 64, row_b0 = bn * 64;
    const int srow = tid >> 3;
    const int gsw  = (((tid & 7) ^ (srow & 7))) * 8;
    const int lsl  = (tid & 7) * 8;

    for (int kt = 0; kt < DINNER; kt += 64) {
        #pragma unroll
        for (int i = 0; i < 2; ++i) {
            int row = srow + i * 32;
            load_lds16(&yb[(size_t)(row_a0 + row) * DINNER + kt + gsw], &As[row * 64 + lsl]);
            load_lds16(&woutb[(size_t)(row_b0 + row) * DINNER + kt + gsw], &Bs[row * 64 + lsl]);
        }
        __syncthreads();
        #pragma unroll
        for (int k0 = 0; k0 < 64; k0 += 32) {
            bf16x8 af[2], bfr[2];
            #pragma unroll
            for (int mi = 0; mi < 2; ++mi) {
                int r = wm + mi * 16 + lr, kc = (k0 >> 3) + q;
                af[mi] = *reinterpret_cast<const bf16x8*>(
                    &As[r * 64 + ((kc ^ (r & 7)) << 3)]);
            }
            #pragma unroll
            for (int ni = 0; ni < 2; ++ni) {
                int r = wn + ni * 16 + lr, kc = (k0 >> 3) + q;
                bfr[ni] = *reinterpret_cast<const bf16x8*>(
                    &Bs[r * 64 + ((kc ^ (r & 7)) << 3)]);
            }
            #pragma unroll
            for (int mi = 0; mi < 2; ++mi)
                #pragma unroll
                for (int ni = 0; ni < 2; ++ni)
                    acc[mi][ni] = __builtin_amdgcn_mfma_f32_16x16x32_bf16(
                        af[mi], bfr[ni], acc[mi][ni], 0, 0, 0);
        }
        __syncthreads();
    }

    float sc[2][4];
    #pragma unroll
    for (int mi = 0; mi < 2; ++mi)
        #pragma unroll
        for (int ri = 0; ri < 4; ++ri) {
            int row = row_a0 + wm + mi * 16 + q * 4 + ri;
            sc[mi][ri] = rsqrtf(ss[row] * (1.f / 1024.f) + 1e-5f);
        }

    #pragma unroll
    for (int mi = 0; mi < 2; ++mi)
        #pragma unroll
        for (int ni = 0; ni < 2; ++ni)
            #pragma unroll
            for (int ri = 0; ri < 4; ++ri) {
                int row = row_a0 + wm + mi * 16 + q * 4 + ri;
                int col = row_b0 + wn + ni * 16 + lr;
                out[(size_t)row * DMODEL + col] = acc[mi][ni][ri] * sc[mi][ri];
            }
}

// ---------------------------------------------------------------------------
// GEMM-A standalone: 64x64 tiles, 2048 blocks, 16 KB LDS.
// ---------------------------------------------------------------------------
__global__ __launch_bounds__(256, 8) void gemmA_kernel(
    const bf16_t* __restrict__ Xt, const bf16_t* __restrict__ Bwt,
    bf16_t* __restrict__ cstate)
{
    __shared__ __align__(16) unsigned char smem[16384];
    int id = blockIdx.x;                // [0,2048)
    int bc = id & 63;                   // chunk; XCD = bc & 7
    int t  = id >> 6;                   // [0,32)
    int bm = t >> 1, bn = t & 1;        // bm [0,16), bn [0,2)
    gemm6464_body<bf16_t>(smem,
        Xt + (size_t)bc * 131072, Bwt + (size_t)bc * 16384,
        cstate + (size_t)bc * 131072,
        DSTATE, CHUNK, CHUNK, CHUNK, bn, bm);
}

// ---------------------------------------------------------------------------
// mbuild64 body (smem 33.5 KB): 64x64-output sub-block (bm,bn in [0,2)).
// ---------------------------------------------------------------------------
__device__ __forceinline__ void mbuild64_body(
    unsigned char* smem,
    const float* __restrict__ sarr, const float* __restrict__ dtv,
    const float* __restrict__ Pv, const float* __restrict__ A_log,
    const bf16_t* __restrict__ xbc, bf16_t* __restrict__ Mx, int sub)
{
    int bc = sub & 63;                  // chunk
    int t  = sub >> 6;                  // [0,4)
    int bm = t >> 1, bn = t & 1;

    bf16_t* Cs  = (bf16_t*)smem;             // 64 x 128 = 16 KB
    bf16_t* Bs2 = (bf16_t*)(smem + 16384);   // 64 x 128 = 16 KB
    float* sj = (float*)(smem + 32768);
    float* dj = sj + 128;
    float* pj = dj + 128;

    int tid = threadIdx.x;
    if (tid < CHUNK) {
        sj[tid] = sarr[bc * CHUNK + tid];
        dj[tid] = dtv[bc * CHUNK + tid];
        pj[tid] = Pv[bc * CHUNK + tid];
    }
    int rowbase = bc * 128;
    int srow = tid >> 4;                     // 0..15
    int gsw  = (((tid & 15) ^ (srow & 7))) * 8;
    int lsl  = (tid & 15) * 8;
    #pragma unroll
    for (int i = 0; i < 4; ++i) {
        int row = srow + i * 16;             // 0..63 local
        load_lds16(&xbc[(size_t)(rowbase + bm * 64 + row) * NCONV + 1152 + gsw],
                   &Cs[row * 128 + lsl]);
        load_lds16(&xbc[(size_t)(rowbase + bn * 64 + row) * NCONV + 1024 + gsw],
                   &Bs2[row * 128 + lsl]);
    }
    __syncthreads();

    const int wave = tid >> 6, lane = tid & 63;
    const int lr = lane & 15, q = lane >> 4;
    const int wm = (wave & 1) * 32, wn = (wave >> 1) * 32;

    f32x4 acc[2][2];
    #pragma unroll
    for (int i = 0; i < 2; ++i)
        #pragma unroll
        for (int j = 0; j < 2; ++j)
            acc[i][j] = (f32x4){0.f, 0.f, 0.f, 0.f};

    #pragma unroll
    for (int k0 = 0; k0 < 128; k0 += 32) {
        bf16x8 af[2], bfr[2];
        #pragma unroll
        for (int mi = 0; mi < 2; ++mi) {
            int r = wm + mi * 16 + lr, kc = (k0 >> 3) + q;
            af[mi] = *reinterpret_cast<const bf16x8*>(
                &Cs[r * 128 + ((kc ^ (r & 7)) << 3)]);
        }
        #pragma unroll
        for (int ni = 0; ni < 2; ++ni) {
            int r = wn + ni * 16 + lr, kc = (k0 >> 3) + q;
            bfr[ni] = *reinterpret_cast<const bf16x8*>(
                &Bs2[r * 128 + ((kc ^ (r & 7)) << 3)]);
        }
        #pragma unroll
        for (int mi = 0; mi < 2; ++mi)
            #pragma unroll
            for (int ni = 0; ni < 2; ++ni)
                acc[mi][ni] = __builtin_amdgcn_mfma_f32_16x16x32_bf16(
                    af[mi], bfr[ni], acc[mi][ni], 0, 0, 0);
    }

    float A = -expf(A_log[0]);
    bf16_t* MxB = Mx + (size_t)bc * 32768;
    #pragma unroll
    for (int mi = 0; mi < 2; ++mi)
        #pragma unroll
        for (int ni = 0; ni < 2; ++ni)
            #pragma unroll
            for (int ri = 0; ri < 4; ++ri) {
                int row = bm * 64 + wm + mi * 16 + q * 4 + ri;
                int col = bn * 64 + wn + ni * 16 + lr;
                float val = 0.f;
                if (col <= row)
                    val = acc[mi][ni][ri] * expf(A * (sj[row] - sj[col])) * dj[col];
                MxB[(size_t)row * 256 + col] = (bf16_t)val;
            }

    // Cw half (bn==0 blocks own full C rows): Mx[row][128+n] = P_row * C[row][n]
    if (bn == 0) {
        int rl = tid >> 2;                   // 0..63 local row
        int cb2 = (tid & 3) * 32;            // 0,32,64,96
        float Pi = pj[bm * 64 + rl];
        #pragma unroll
        for (int m0 = 0; m0 < 32; m0 += 8) {
            int kc = (cb2 + m0) >> 3;
            bf16x8 cv = *reinterpret_cast<const bf16x8*>(
                &Cs[rl * 128 + ((kc ^ (rl & 7)) << 3)]);
            bf16x8 o;
            #pragma unroll
            for (int m = 0; m < 8; ++m) o[m] = (bf16_t)((float)cv[m] * Pi);
            *reinterpret_cast<bf16x8*>(
                &MxB[(size_t)(bm * 64 + rl) * 256 + 128 + cb2 + m0]) = o;
        }
    }
}

// ---------------------------------------------------------------------------
// scan_combine body: S_init(c) = chp*S_init + S_loc (prefetch-all).
// ---------------------------------------------------------------------------
__device__ __forceinline__ void scan_body(
    unsigned char* smem,
    const bf16_t* __restrict__ cstate, const float* __restrict__ chp,
    bf16_t* __restrict__ Stb, int blk)
{
    float* chS = (float*)smem;
    int idx = blk * 256 + threadIdx.x;   // B * 131072
    int b   = idx >> 17;
    int np  = idx & 131071;
    if (threadIdx.x < NCHUNK) chS[threadIdx.x] = chp[b * NCHUNK + threadIdx.x];
    __syncthreads();

    const bf16_t* src = cstate + ((size_t)b << 21) + np;
    bf16_t*       dst = Stb    + ((size_t)b << 21) + np;
    float t[NCHUNK];
    #pragma unroll
    for (int c = 0; c < NCHUNK; ++c) t[c] = (float)src[(size_t)c << 17];
    float v = 0.f;
    #pragma unroll
    for (int c = 0; c < NCHUNK; ++c) {
        dst[(size_t)c << 17] = (bf16_t)v;
        v = chS[c] * v + t[c];
    }
}

// Merged: mbuild64 (0..255) + scan_combine (256..2303) + ss-zero (2304..2335)
__global__ __launch_bounds__(256) void scan_mbuild_kernel(
    const bf16_t* __restrict__ cstate, const float* __restrict__ chp,
    bf16_t* __restrict__ Stb,
    const float* __restrict__ sarr, const float* __restrict__ dtv,
    const float* __restrict__ Pv, const float* __restrict__ A_log,
    const bf16_t* __restrict__ xbc, bf16_t* __restrict__ Mx,
    float* __restrict__ ss)
{
    __shared__ __align__(16) unsigned char smem[34304];
    int id = blockIdx.x;
    if (id < 256) {
        mbuild64_body(smem, sarr, dtv, Pv, A_log, xbc, Mx, id);
    } else if (id < 256 + BATCH * 131072 / 256) {
        scan_body(smem, cstate, chp, Stb, id - 256);
    } else {
        int i = (id - 256 - BATCH * 131072 / 256) * 256 + threadIdx.x;
        ss[i] = 0.f;                     // 32 blocks x 256 = 8192
    }
}

// ---------------------------------------------------------------------------
// Y-GEMM + fused gate: 64x64 tiles, 2048 blocks, chunk->XCD grouped.
// Y[i,p] = sum_{k<256} Mx[i,k]*Dx[p,k]; then epilogue: LDS acc transpose
// (16B-unit XOR swizzle), g=(y+D*x)*silu(z), write yb, atomic row sum(g^2).
// ---------------------------------------------------------------------------
__global__ __launch_bounds__(256, 8) void gemm_y_kernel(
    const bf16_t* __restrict__ Mx, const bf16_t* __restrict__ Xt,
    const bf16_t* __restrict__ Stb, const bf16_t* __restrict__ zx,
    const bf16_t* __restrict__ xbc, const float* __restrict__ Dp,
    bf16_t* __restrict__ yb, float* __restrict__ ss)
{
    __shared__ __align__(16) bf16_t As[64 * 64];    //  8 KB
    __shared__ __align__(16) bf16_t Bs[64 * 64];    //  8 KB

    int id = blockIdx.x;                // [0,2048)
    int bc = id & 63;                   // chunk; XCD = bc & 7
    int t  = id >> 6;                   // [0,32)
    int half = t & 1, bn = t >> 1;      // row half [0,2), col tile [0,16)

    const bf16_t* Ab = Mx  + (size_t)bc * 32768 + (size_t)half * 64 * 256;   // 64x256
    const bf16_t* Xb = Xt  + (size_t)bc * 131072 + (size_t)bn * 64 * 128;
    const bf16_t* Sb = Stb + (size_t)bc * 131072 + (size_t)bn * 64 * 128;

    const int tid  = threadIdx.x;
    const int wave = tid >> 6, lane = tid & 63;
    const int lr = lane & 15, q = lane >> 4;
    const int wm = (wave & 1) * 32, wn = (wave >> 1) * 32;

    f32x4 acc[2][2];
    #pragma unroll
    for (int i = 0; i < 2; ++i)
        #pragma unroll
        for (int j = 0; j < 2; ++j)
            acc[i][j] = (f32x4){0.f, 0.f, 0.f, 0.f};

    const int srow = tid >> 3;
    const int gsw  = (((tid & 7) ^ (srow & 7))) * 8;
    const int lsl  = (tid & 7) * 8;

    for (int kt = 0; kt < 256; kt += 64) {
        const bf16_t* bsrc = (kt < 128) ? (Xb + kt) : (Sb + (kt - 128));
        #pragma unroll
        for (int i = 0; i < 2; ++i) {
            int row = srow + i * 32;
            load_lds16(&Ab[(size_t)row * 256 + kt + gsw], &As[row * 64 + lsl]);
            load_lds16(&bsrc[(size_t)row * 128 + gsw], &Bs[row * 64 + lsl]);
        }
        __syncthreads();
        #pragma unroll
        for (int k0 = 0; k0 < 64; k0 += 32) {
            bf16x8 af[2], bfr[2];
            #pragma unroll
            for (int mi = 0; mi < 2; ++mi) {
                int r = wm + mi * 16 + lr, kc = (k0 >> 3) + q;
                af[mi] = *reinterpret_cast<const bf16x8*>(
                    &As[r * 64 + ((kc ^ (r & 7)) << 3)]);
            }
            #pragma unroll
            for (int ni = 0; ni < 2; ++ni) {
                int r = wn + ni * 16 + lr, kc = (k0 >> 3) + q;
                bfr[ni] = *reinterpret_cast<const bf16x8*>(
                    &Bs[r * 64 + ((kc ^ (r & 7)) << 3)]);
            }
            #pragma unroll
            for (int mi = 0; mi < 2; ++mi)
                #pragma unroll
                for (int ni = 0; ni < 2; ++ni)
                    acc[mi][ni] = __builtin_amdgcn_mfma_f32_16x16x32_bf16(
                        af[mi], bfr[ni], acc[mi][ni], 0, 0, 0);
        }
        __syncthreads();
    }

    // ---- fused gate epilogue ----
    // Stage 64x64 acc tile into LDS (reuse As), swizzled at 16B-unit level:
    // unit(row,colgrp) = (row*8 + colgrp) ^ (row&7) -- conflict-free for the
    // scattered MFMA-layout writes AND the row-linear 16B reads.
    bf16_t* Yt = As;
    #pragma unroll
    for (int mi = 0; mi < 2; ++mi)
        #pragma unroll
        for (int ni = 0; ni < 2; ++ni)
            #pragma unroll
            for (int ri = 0; ri < 4; ++ri) {
                int row = wm + mi * 16 + q * 4 + ri;     // [0,64)
                int col = wn + ni * 16 + lr;             // [0,64)
                int u = (row * 8 + (col >> 3)) ^ (row & 7);
                Yt[u * 8 + (col & 7)] = (bf16_t)acc[mi][ni][ri];
            }
    __syncthreads();

    const int rr = tid >> 2, cq = tid & 3;               // row, col-quarter
    const size_t rg = (size_t)bc * 128 + half * 64 + rr; // global row
    const float D0 = Dp[0];
    float part = 0.f;
    #pragma unroll
    for (int j = 0; j < 2; ++j) {
        int u = (rr * 8 + cq * 2 + j) ^ (rr & 7);
        bf16x8 yv = *reinterpret_cast<const bf16x8*>(&Yt[u * 8]);
        int colg = bn * 64 + cq * 16 + j * 8;            // [0,1024)
        bf16x8 zv = *reinterpret_cast<const bf16x8*>(zx  + rg * NZX   + colg);
        bf16x8 xv = *reinterpret_cast<const bf16x8*>(xbc + rg * NCONV + colg);
        bf16x8 o;
        #pragma unroll
        for (int m = 0; m < 8; ++m) {
            float g = ((float)yv[m] + D0 * (float)xv[m]) * siluf((float)zv[m]);
            part += g * g;
            o[m] = (bf16_t)g;
        }
        *reinterpret_cast<bf16x8*>(yb + rg * DINNER + colg) = o;
    }
    part += __shfl_xor(part, 1);
    part += __shfl_xor(part, 2);
    if ((tid & 3) == 0) atomicAdd(&ss[rg], part);
}

// ---------------------------------------------------------------------------
// Fused: dt column + x->bf16 cast [blocks 0..2047], then W_in cast /
// W_out*norm_w cast / rnn passthrough tails.
// ---------------------------------------------------------------------------
__global__ __launch_bounds__(256) void dtcast_kernel(
    const float* __restrict__ x, const float* __restrict__ W_in,
    const float* __restrict__ dt_bias, const float* __restrict__ W_out,
    const float* __restrict__ norm_w, const float* __restrict__ rnn,
    float* __restrict__ dtv, bf16_t* __restrict__ xb,
    bf16_t* __restrict__ winb, bf16_t* __restrict__ woutb,
    float* __restrict__ outTail)
{
    int bid = blockIdx.x;
    if (bid < MROWS / 4) {
        int wave = threadIdx.x >> 6, lane = threadIdx.x & 63;
        int r = bid * 4 + wave;
        const float* xr = x + (size_t)r * DMODEL + lane * 8;
        const float* wr = W_in + (size_t)NZX * DMODEL + lane * 8;
        float4 a0 = *reinterpret_cast<const float4*>(xr);
        float4 a1 = *reinterpret_cast<const float4*>(xr + 4);
        float4 b0 = *reinterpret_cast<const float4*>(wr);
        float4 b1 = *reinterpret_cast<const float4*>(wr + 4);

        bf16x8 xo;
        xo[0] = (bf16_t)a0.x; xo[1] = (bf16_t)a0.y; xo[2] = (bf16_t)a0.z; xo[3] = (bf16_t)a0.w;
        xo[4] = (bf16_t)a1.x; xo[5] = (bf16_t)a1.y; xo[6] = (bf16_t)a1.z; xo[7] = (bf16_t)a1.w;
        *reinterpret_cast<bf16x8*>(xb + (size_t)r * DMODEL + lane * 8) = xo;

        float s = a0.x * b0.x + a0.y * b0.y + a0.z * b0.z + a0.w * b0.w
                + a1.x * b1.x + a1.y * b1.y + a1.z * b1.z + a1.w * b1.w;
        #pragma unroll
        for (int m = 32; m >= 1; m >>= 1) s += __shfl_xor(s, m);
        if (lane == 0) {
            float t  = s + dt_bias[0];
            dtv[r] = (t > 20.f) ? t : log1pf(expf(t));
        }
        return;
    }
    int i = (bid - MROWS / 4) * 256 + threadIdx.x;
    const int n4a = 2305 * DMODEL / 4, n4b = DMODEL * DINNER / 4;
    if (i < n4a) {
        float4 v = reinterpret_cast<const float4*>(W_in)[i];
        bf16x4 o;
        o[0] = (bf16_t)v.x; o[1] = (bf16_t)v.y; o[2] = (bf16_t)v.z; o[3] = (bf16_t)v.w;
        reinterpret_cast<bf16x4*>(winb)[i] = o;
    } else if (i < n4a + n4b) {
        int j = i - n4a;
        float4 v = reinterpret_cast<const float4*>(W_out)[j];
        int c0 = (j * 4) & (DINNER - 1);
        float4 w = *reinterpret_cast<const float4*>(norm_w + c0);
        bf16x4 o;
        o[0] = (bf16_t)(v.x * w.x); o[1] = (bf16_t)(v.y * w.y);
        o[2] = (bf16_t)(v.z * w.z); o[3] = (bf16_t)(v.w * w.w);
        reinterpret_cast<bf16x4*>(woutb)[j] = o;
    } else if (i < n4a + n4b + BATCH * DMODEL) {
        int k = i - n4a - n4b;
        outTail[k] = rnn[k];
    }
}

// ---------------------------------------------------------------------------
// Fused conv + transpose (R11 layout): 1280 blocks, 128x64 tile, TS=66.
// ---------------------------------------------------------------------------
__global__ __launch_bounds__(256, 6) void conv_tr_kernel(
    const bf16_t* __restrict__ zx, const float* __restrict__ cw,
    const float* __restrict__ cb, const float* __restrict__ EdTv,
    bf16_t* __restrict__ xbc, bf16_t* __restrict__ Xt, bf16_t* __restrict__ Bwt)
{
    constexpr int TS = 66;                 // 132B row stride = 33 banks (odd)
    __shared__ bf16_t tile[128 * TS];      // [j][ch_local]
    __shared__ float cwS[64 * 4];
    __shared__ float cbS[64];

    int id  = blockIdx.x;                  // [0,1280)
    int xcd = id & 7;
    int k   = id >> 3;                     // [0,160)
    int bc  = xcd * 8 + (k & 7);           // zx band bc lives in XCD bc>>3 L2
    int rest = k >> 3;                     // [0,20)
    int cg   = rest >> 1;                  // [0,10)
    int half = rest & 1;
    int c0   = cg * 128 + half * 64;       // global channel base in [0,1280)
    int tid  = threadIdx.x;

    if (tid < 64) {
        float4 w = *reinterpret_cast<const float4*>(cw + (size_t)(c0 + tid) * 4);
        *reinterpret_cast<float4*>(&cwS[tid * 4]) = w;
        cbS[tid] = cb[c0 + tid];
    }
    __syncthreads();

    int lrow = tid >> 3;                   // 0..31
    int lc8  = (tid & 7) * 8;              // 0..56 (channel-local)
    int g0 = bc * 128;

    #pragma unroll
    for (int pass = 0; pass < 4; ++pass) {
        int row = pass * 32 + lrow;        // j in chunk
        int g = g0 + row;
        int l = g & (SEQLEN - 1);
        float acc[8];
        #pragma unroll
        for (int m = 0; m < 8; ++m) acc[m] = cbS[lc8 + m];
        #pragma unroll
        for (int kk = 0; kk < 4; ++kk) {
            if (l + kk >= 3) {
                bf16x8 v = *reinterpret_cast<const bf16x8*>(
                    zx + (size_t)(g + kk - 3) * NZX + DINNER + c0 + lc8);
                #pragma unroll
                for (int m = 0; m < 8; ++m)
                    acc[m] += cwS[(lc8 + m) * 4 + kk] * (float)v[m];
            }
        }
        bf16x8 o;
        #pragma unroll
        for (int m = 0; m < 8; ++m) o[m] = (bf16_t)siluf(acc[m]);
        *reinterpret_cast<bf16x8*>(xbc + (size_t)g * NCONV + c0 + lc8) = o;
        if (cg < 9) {
            #pragma unroll
            for (int jj = 0; jj < 4; ++jj) {
                bf16x2 p; p[0] = o[jj * 2]; p[1] = o[jj * 2 + 1];
                *reinterpret_cast<bf16x2*>(&tile[row * TS + lc8 + jj * 2]) = p;
            }
        }
    }
    if (cg == 9) return;
    __syncthreads();

    const bool isB = (cg == 8);
    int jo = (tid >> 4) * 8;               // j-block 0..120
    int i  = tid & 15;
    float sc[8];
    #pragma unroll
    for (int m = 0; m < 8; ++m)
        sc[m] = isB ? EdTv[bc * 128 + jo + m] : 1.f;

    #pragma unroll
    for (int pass = 0; pass < 4; ++pass) {
        int oc = pass * 16 + i;            // channel-local 0..63
        bf16x8 o;
        #pragma unroll
        for (int m = 0; m < 8; ++m)
            o[m] = (bf16_t)((float)tile[(jo + m) * TS + oc] * sc[m]);
        bf16_t* dst = isB
            ? (Bwt + (size_t)bc * 16384 + (size_t)(c0 - 1024 + oc) * 128 + jo)
            : (Xt + (size_t)bc * 131072 + (size_t)(c0 + oc) * 128 + jo);
        *reinterpret_cast<bf16x8*>(dst) = o;
    }
}

// ---------------------------------------------------------------------------
extern "C" void kernel_launch(void* const* d_in, const int* in_sizes, int n_in,
                              void* d_out, int out_size, void* d_ws, size_t ws_size,
                              hipStream_t stream)
{
    const float* x        = (const float*)d_in[0];
    const float* rnn      = (const float*)d_in[1];
    const float* W_in     = (const float*)d_in[2];
    const float* conv_w   = (const float*)d_in[3];
    const float* conv_b   = (const float*)d_in[4];
    const float* dt_bias  = (const float*)d_in[5];
    const float* A_log    = (const float*)d_in[6];
    const float* Dp       = (const float*)d_in[7];
    const float* norm_w   = (const float*)d_in[8];
    const float* W_out    = (const float*)d_in[9];
    float* out = (float*)d_out;

    // workspace carve
    char* ws = (char*)d_ws;
    bf16_t* xb     = (bf16_t*)(ws + 0);                       //  8,388,608 (dead after GEMM1)
    float*  ssn    = (float*) (ws + 0);                       //     32,768 (alias over dead xb head)
    bf16_t* Mx     = (bf16_t*)(ws + 4194304);                 //  4,194,304 (alias over xb tail)
    bf16_t* winb   = (bf16_t*)(ws + 8388608);                 //  2,360,320
    bf16_t* woutb  = (bf16_t*)(ws + 10748928);                //  1,048,576
    bf16_t* zx     = (bf16_t*)(ws + 11797504);                // 37,748,736
    float*  dtv    = (float*) (ws + 49546240);                //     32,768
    float*  sarr   = (float*) (ws + 49579008);                //     32,768
    float*  Pv     = (float*) (ws + 49611776);                //     32,768
    float*  EdTv   = (float*) (ws + 49644544);                //     32,768
    float*  chp    = (float*) (ws + 49677312);                //        256
    bf16_t* xbcb   = (bf16_t*)(ws + 49677568);                // 20,971,520
    bf16_t* Xt     = (bf16_t*)(ws + 70649088);                // 16,777,216
    bf16_t* Bwt    = (bf16_t*)(ws + 87426304);                //  2,097,152
    bf16_t* cstate = (bf16_t*)(ws + 89523456);                // 16,777,216 (S_loc bf16)
    bf16_t* Stb    = (bf16_t*)(ws + 106300672);               // 16,777,216
    bf16_t* yb     = (bf16_t*)(ws + 123077888);               // 16,777,216
    // end: 139,855,104 bytes

    // 1) dt (fp32) + x cast + weight casts (+norm_w fold) + rnn passthrough
    {
        const int n4a = 2305 * DMODEL / 4, n4b = DMODEL * DINNER / 4;
        int nrest = n4a + n4b + BATCH * DMODEL;
        int grid = MROWS / 4 + (nrest + 255) / 256;
        dtcast_kernel<<<grid, 256, 0, stream>>>(
            x, W_in, dt_bias, W_out, norm_w, rnn, dtv, xb, winb, woutb,
            out + (size_t)MROWS * DMODEL);
    }

    // 2) GEMM1 (64x128 tiles, 2304 blocks + fused cumsum tail blocks)
    gemm1_kernel<<<2304 + NBC, 256, 0, stream>>>(
        xb, winb, zx, dtv, A_log, sarr, Pv, EdTv, chp);

    // 3) fused conv + transpose (1280 blocks, XCD-matched to zx bands)
    conv_tr_kernel<<<1280, 256, 0, stream>>>(
        zx, conv_w, conv_b, EdTv, xbcb, Xt, Bwt);

    // 4) GEMM-A standalone: 64x64 tiles, 2048 blocks, 16 KB LDS
    gemmA_kernel<<<2048, 256, 0, stream>>>(Xt, Bwt, cstate);

    // 5) mbuild64 (256) + combine -> Stb (2048) + ss-zero (32), merged
    scan_mbuild_kernel<<<256 + BATCH * 131072 / 256 + 32, 256, 0, stream>>>(
        cstate, chp, Stb, sarr, dtv, Pv, A_log, xbcb, Mx, ssn);

    // 6) GEMM-Y + fused gate: yb = g bf16, ss += row sums
    gemm_y_kernel<<<2048, 256, 0, stream>>>(
        Mx, Xt, Stb, zx, xbcb, Dp, yb, ssn);

    // 7) GEMM2 (+RMSNorm scale epilogue, norm_w pre-folded into woutb)
    gemm2_kernel<<<1024, 256, 0, stream>>>(yb, woutb, ssn, out);
}

// Round 8
// 178.982 us; speedup vs baseline: 1.2424x; 1.2424x over previous
//
#include <hip/hip_runtime.h>
#include <cstdint>
#include <cstddef>

// ---------------------------------------------------------------------------
// Mamba2 layer forward (B=4, L=2048, d_model=512, d_inner=1024, d_state=128,
// nheads=1, d_conv=4). SSD formulation: scan as chunked bf16 MFMA GEMMs.
// R5 SSD 609->281; R6 global_load_lds; R7 XOR-swizzle; R8 fusion ->233;
// R10 XCD swizzle; R11 conv_tr odd-bank tile ->219; R12 wave-per-row
// gate_norm ->214. R13 GEMM2 64x128 retile ->206. R14 gate fusion regressed
// at low occupancy. R15/16 gemm_y retile ->202.8. R17 gemm1 64x128 ->193.6.
// R18 occupancy audit (64x64 everywhere) ->190.2. R19 gate+RMSNorm fusion
// re-applied at high occupancy (7 launches) ->186.3.
// R20 __launch_bounds__ VGPR-cap REGRESSED (222us): compiler met the bound
// by SPILLING acc to scratch (gemm1 VGPR 40, WRITE 120MB vs 38 ideal,
// dur 71.7us). Lever dead. R21: pure revert to R19.
// ---------------------------------------------------------------------------

typedef __bf16 bf16_t;
typedef __bf16 bf16x8 __attribute__((ext_vector_type(8)));
typedef __bf16 bf16x4 __attribute__((ext_vector_type(4)));
typedef __bf16 bf16x2 __attribute__((ext_vector_type(2)));
typedef float  f32x4  __attribute__((ext_vector_type(4)));

#define BATCH   4
#define SEQLEN  2048
#define MROWS   8192
#define DMODEL  512
#define DINNER  1024
#define DSTATE  128
#define NZX     2304
#define NCONV   1280
#define CHUNK   128
#define NCHUNK  16
#define NBC     64            // BATCH * NCHUNK

__device__ __forceinline__ float siluf(float x) { return x / (1.f + __expf(-x)); }

// async global->LDS, 16B per lane. LDS dst is wave-uniform base + lane*16.
__device__ __forceinline__ void load_lds16(const bf16_t* g, bf16_t* l)
{
    __builtin_amdgcn_global_load_lds(
        (const __attribute__((address_space(1))) void*)g,
        (__attribute__((address_space(3))) void*)l,
        16, 0, 0);
}

// ---------------------------------------------------------------------------
// 64x128-tile GEMM body (smem 24 KB): BK=64, XOR-swizzled global_load_lds
// staging, per-wave 32x64 (acc[2][4]), 4 waves = 2M x 2N.
// ---------------------------------------------------------------------------
template <typename OutT>
__device__ __forceinline__ void gemm64_body(
    unsigned char* smem,
    const bf16_t* __restrict__ A, const bf16_t* __restrict__ B,
    OutT* __restrict__ C, int Ntot, int K, int lda, int ldb, int bn, int bm)
{
    bf16_t* As = (bf16_t*)smem;            // 64 x 64  =  8 KB
    bf16_t* Bs = (bf16_t*)(smem + 8192);   // 128 x 64 = 16 KB

    const int tid  = threadIdx.x;
    const int wave = tid >> 6, lane = tid & 63;
    const int lr = lane & 15, q = lane >> 4;
    const int wm = (wave & 1) * 32, wn = (wave >> 1) * 64;

    f32x4 acc[2][4];
    #pragma unroll
    for (int i = 0; i < 2; ++i)
        #pragma unroll
        for (int j = 0; j < 4; ++j)
            acc[i][j] = (f32x4){0.f, 0.f, 0.f, 0.f};

    const int row_a0 = bm * 64, row_b0 = bn * 128;
    const int srow = tid >> 3;
    const int gsw  = (((tid & 7) ^ (srow & 7))) * 8;
    const int lsl  = (tid & 7) * 8;

    for (int kt = 0; kt < K; kt += 64) {
        #pragma unroll
        for (int i = 0; i < 2; ++i) {
            int row = srow + i * 32;
            load_lds16(&A[(size_t)(row_a0 + row) * lda + kt + gsw], &As[row * 64 + lsl]);
        }
        #pragma unroll
        for (int i = 0; i < 4; ++i) {
            int row = srow + i * 32;
            load_lds16(&B[(size_t)(row_b0 + row) * ldb + kt + gsw], &Bs[row * 64 + lsl]);
        }
        __syncthreads();
        #pragma unroll
        for (int k0 = 0; k0 < 64; k0 += 32) {
            bf16x8 af[2], bfr[4];
            #pragma unroll
            for (int mi = 0; mi < 2; ++mi) {
                int r = wm + mi * 16 + lr, kc = (k0 >> 3) + q;
                af[mi] = *reinterpret_cast<const bf16x8*>(
                    &As[r * 64 + ((kc ^ (r & 7)) << 3)]);
            }
            #pragma unroll
            for (int ni = 0; ni < 4; ++ni) {
                int r = wn + ni * 16 + lr, kc = (k0 >> 3) + q;
                bfr[ni] = *reinterpret_cast<const bf16x8*>(
                    &Bs[r * 64 + ((kc ^ (r & 7)) << 3)]);
            }
            #pragma unroll
            for (int mi = 0; mi < 2; ++mi)
                #pragma unroll
                for (int ni = 0; ni < 4; ++ni)
                    acc[mi][ni] = __builtin_amdgcn_mfma_f32_16x16x32_bf16(
                        af[mi], bfr[ni], acc[mi][ni], 0, 0, 0);
        }
        __syncthreads();
    }

    #pragma unroll
    for (int mi = 0; mi < 2; ++mi)
        #pragma unroll
        for (int ni = 0; ni < 4; ++ni)
            #pragma unroll
            for (int ri = 0; ri < 4; ++ri) {
                int row = row_a0 + wm + mi * 16 + q * 4 + ri;
                int col = row_b0 + wn + ni * 16 + lr;
                C[(size_t)row * Ntot + col] = (OutT)acc[mi][ni][ri];
            }
}

// ---------------------------------------------------------------------------
// 64x64-tile GEMM body (smem 16 KB): BK=64, per-wave 32x32 (acc[2][2]),
// 4 waves = 2M x 2N. Same staging/swizzle/accumulation order as gemm64_body.
// ---------------------------------------------------------------------------
template <typename OutT>
__device__ __forceinline__ void gemm6464_body(
    unsigned char* smem,
    const bf16_t* __restrict__ A, const bf16_t* __restrict__ B,
    OutT* __restrict__ C, int Ntot, int K, int lda, int ldb, int bn, int bm)
{
    bf16_t* As = (bf16_t*)smem;            // 64 x 64 = 8 KB
    bf16_t* Bs = (bf16_t*)(smem + 8192);   // 64 x 64 = 8 KB

    const int tid  = threadIdx.x;
    const int wave = tid >> 6, lane = tid & 63;
    const int lr = lane & 15, q = lane >> 4;
    const int wm = (wave & 1) * 32, wn = (wave >> 1) * 32;

    f32x4 acc[2][2];
    #pragma unroll
    for (int i = 0; i < 2; ++i)
        #pragma unroll
        for (int j = 0; j < 2; ++j)
            acc[i][j] = (f32x4){0.f, 0.f, 0.f, 0.f};

    const int row_a0 = bm * 64, row_b0 = bn * 64;
    const int srow = tid >> 3;
    const int gsw  = (((tid & 7) ^ (srow & 7))) * 8;
    const int lsl  = (tid & 7) * 8;

    for (int kt = 0; kt < K; kt += 64) {
        #pragma unroll
        for (int i = 0; i < 2; ++i) {
            int row = srow + i * 32;
            load_lds16(&A[(size_t)(row_a0 + row) * lda + kt + gsw], &As[row * 64 + lsl]);
            load_lds16(&B[(size_t)(row_b0 + row) * ldb + kt + gsw], &Bs[row * 64 + lsl]);
        }
        __syncthreads();
        #pragma unroll
        for (int k0 = 0; k0 < 64; k0 += 32) {
            bf16x8 af[2], bfr[2];
            #pragma unroll
            for (int mi = 0; mi < 2; ++mi) {
                int r = wm + mi * 16 + lr, kc = (k0 >> 3) + q;
                af[mi] = *reinterpret_cast<const bf16x8*>(
                    &As[r * 64 + ((kc ^ (r & 7)) << 3)]);
            }
            #pragma unroll
            for (int ni = 0; ni < 2; ++ni) {
                int r = wn + ni * 16 + lr, kc = (k0 >> 3) + q;
                bfr[ni] = *reinterpret_cast<const bf16x8*>(
                    &Bs[r * 64 + ((kc ^ (r & 7)) << 3)]);
            }
            #pragma unroll
            for (int mi = 0; mi < 2; ++mi)
                #pragma unroll
                for (int ni = 0; ni < 2; ++ni)
                    acc[mi][ni] = __builtin_amdgcn_mfma_f32_16x16x32_bf16(
                        af[mi], bfr[ni], acc[mi][ni], 0, 0, 0);
        }
        __syncthreads();
    }

    #pragma unroll
    for (int mi = 0; mi < 2; ++mi)
        #pragma unroll
        for (int ni = 0; ni < 2; ++ni)
            #pragma unroll
            for (int ri = 0; ri < 4; ++ri) {
                int row = row_a0 + wm + mi * 16 + q * 4 + ri;
                int col = row_b0 + wn + ni * 16 + lr;
                C[(size_t)row * Ntot + col] = (OutT)acc[mi][ni][ri];
            }
}

// ---------------------------------------------------------------------------
// cumsum body (per chunk bc, active threads 0..127): decay scalars.
// ---------------------------------------------------------------------------
__device__ __forceinline__ void cumsum_body(
    const float* __restrict__ dtv, const float* __restrict__ A_log,
    float* __restrict__ sarr, float* __restrict__ Pv,
    float* __restrict__ EdTv, float* __restrict__ chp, int bc)
{
    __shared__ float w0sum, stot;
    int j = threadIdx.x;
    bool active = j < CHUNK;
    int lane = j & 63;
    int r = bc * CHUNK + j;
    float A = -expf(A_log[0]);
    float dt = active ? dtv[r] : 0.f;
    float s = dt;
    #pragma unroll
    for (int m = 1; m <= 32; m <<= 1) {
        float o = __shfl_up(s, m);
        if (lane >= m) s += o;
    }
    if (j == 63) w0sum = s;
    __syncthreads();
    if (j >= 64 && active) s += w0sum;
    if (j == 127) stot = s;
    __syncthreads();
    if (active) {
        float sT = stot;
        sarr[r] = s;
        Pv[r]   = expf(A * s);
        EdTv[r] = expf(A * (sT - s)) * dt;
        if (j == 127) chp[bc] = expf(A * sT);
    }
}

// GEMM1 (64x128 tiles, 2304 blocks, XCD bm bands) + cumsum tail blocks
__global__ __launch_bounds__(256) void gemm1_kernel(
    const bf16_t* __restrict__ xb, const bf16_t* __restrict__ winb,
    bf16_t* __restrict__ zx, const float* __restrict__ dtv,
    const float* __restrict__ A_log, float* __restrict__ sarr,
    float* __restrict__ Pv, float* __restrict__ EdTv, float* __restrict__ chp)
{
    __shared__ __align__(16) unsigned char smem[24576];
    int linear = blockIdx.x;
    if (linear < (NZX / 128) * (MROWS / 64)) {      // 18*128 = 2304
        int xcd = linear & 7, j = linear >> 3;      // j in [0,288)
        int bm = xcd * 16 + (j & 15);               // 16-row-tile band per XCD
        int bn = j >> 4;                            // [0,18)
        gemm64_body<bf16_t>(smem, xb, winb, zx, NZX, DMODEL, DMODEL, DMODEL, bn, bm);
    } else {
        cumsum_body(dtv, A_log, sarr, Pv, EdTv, chp, linear - 2304);
    }
}

// ---------------------------------------------------------------------------
// GEMM2: 64x64 tiles, 1024 blocks, XCD bands; out = (yb @ woutb^T)
// * rsqrt(ss/1024 + eps) per row. woutb carries norm_w (folded at cast).
// ---------------------------------------------------------------------------
__global__ __launch_bounds__(256) void gemm2_kernel(
    const bf16_t* __restrict__ yb, const bf16_t* __restrict__ woutb,
    const float* __restrict__ ss, float* __restrict__ out)
{
    __shared__ __align__(16) bf16_t As[64 * 64];
    __shared__ __align__(16) bf16_t Bs[64 * 64];

    int id  = blockIdx.x;              // [0,1024)
    int xcd = id & 7, j = id >> 3;     // j in [0,128)
    int bm  = xcd * 16 + (j & 15);     // [0,128)
    int bn  = j >> 4;                  // [0,8)

    const int tid  = threadIdx.x;
    const int wave = tid >> 6, lane = tid & 63;
    const int lr = lane & 15, q = lane >> 4;
    const int wm = (wave & 1) * 32, wn = (wave >> 1) * 32;

    f32x4 acc[2][2];
    #pragma unroll
    for (int i = 0; i < 2; ++i)
        #pragma unroll
        for (int jj = 0; jj < 2; ++jj)
            acc[i][jj] = (f32x4){0.f, 0.f, 0.f, 0.f};

    const int row_a0 = bm * 64, row_b0 = bn * 64;
    const int srow = tid >> 3;
    const int gsw  = (((tid & 7) ^ (srow & 7))) * 8;
    const int lsl  = (tid & 7) * 8;

    for (int kt = 0; kt < DINNER; kt += 64) {
        #pragma unroll
        for (int i = 0; i < 2; ++i) {
            int row = srow + i * 32;
            load_lds16(&yb[(size_t)(row_a0 + row) * DINNER + kt + gsw], &As[row * 64 + lsl]);
            load_lds16(&woutb[(size_t)(row_b0 + row) * DINNER + kt + gsw], &Bs[row * 64 + lsl]);
        }
        __syncthreads();
        #pragma unroll
        for (int k0 = 0; k0 < 64; k0 += 32) {
            bf16x8 af[2], bfr[2];
            #pragma unroll
            for (int mi = 0; mi < 2; ++mi) {
                int r = wm + mi * 16 + lr, kc = (k0 >> 3) + q;
                af[mi] = *reinterpret_cast<const bf16x8*>(
                    &As[r * 64 + ((kc ^ (r & 7)) << 3)]);
            }
            #pragma unroll
            for (int ni = 0; ni < 2; ++ni) {
                int r = wn + ni * 16 + lr, kc = (k0 >> 3) + q;
                bfr[ni] = *reinterpret_cast<const bf16x8*>(
                    &Bs[r * 64 + ((kc ^ (r & 7)) << 3)]);
            }
            #pragma unroll
            for (int mi = 0; mi < 2; ++mi)
                #pragma unroll
                for (int ni = 0; ni < 2; ++ni)
                    acc[mi][ni] = __builtin_amdgcn_mfma_f32_16x16x32_bf16(
                        af[mi], bfr[ni], acc[mi][ni], 0, 0, 0);
        }
        __syncthreads();
    }

    float sc[2][4];
    #pragma unroll
    for (int mi = 0; mi < 2; ++mi)
        #pragma unroll
        for (int ri = 0; ri < 4; ++ri) {
            int row = row_a0 + wm + mi * 16 + q * 4 + ri;
            sc[mi][ri] = rsqrtf(ss[row] * (1.f / 1024.f) + 1e-5f);
        }

    #pragma unroll
    for (int mi = 0; mi < 2; ++mi)
        #pragma unroll
        for (int ni = 0; ni < 2; ++ni)
            #pragma unroll
            for (int ri = 0; ri < 4; ++ri) {
                int row = row_a0 + wm + mi * 16 + q * 4 + ri;
                int col = row_b0 + wn + ni * 16 + lr;
                out[(size_t)row * DMODEL + col] = acc[mi][ni][ri] * sc[mi][ri];
            }
}

// ---------------------------------------------------------------------------
// GEMM-A standalone: 64x64 tiles, 2048 blocks, 16 KB LDS.
// ---------------------------------------------------------------------------
__global__ __launch_bounds__(256) void gemmA_kernel(
    const bf16_t* __restrict__ Xt, const bf16_t* __restrict__ Bwt,
    bf16_t* __restrict__ cstate)
{
    __shared__ __align__(16) unsigned char smem[16384];
    int id = blockIdx.x;                // [0,2048)
    int bc = id & 63;                   // chunk; XCD = bc & 7
    int t  = id >> 6;                   // [0,32)
    int bm = t >> 1, bn = t & 1;        // bm [0,16), bn [0,2)
    gemm6464_body<bf16_t>(smem,
        Xt + (size_t)bc * 131072, Bwt + (size_t)bc * 16384,
        cstate + (size_t)bc * 131072,
        DSTATE, CHUNK, CHUNK, CHUNK, bn, bm);
}

// ---------------------------------------------------------------------------
// mbuild64 body (smem 33.5 KB): 64x64-output sub-block (bm,bn in [0,2)).
// ---------------------------------------------------------------------------
__device__ __forceinline__ void mbuild64_body(
    unsigned char* smem,
    const float* __restrict__ sarr, const float* __restrict__ dtv,
    const float* __restrict__ Pv, const float* __restrict__ A_log,
    const bf16_t* __restrict__ xbc, bf16_t* __restrict__ Mx, int sub)
{
    int bc = sub & 63;                  // chunk
    int t  = sub >> 6;                  // [0,4)
    int bm = t >> 1, bn = t & 1;

    bf16_t* Cs  = (bf16_t*)smem;             // 64 x 128 = 16 KB
    bf16_t* Bs2 = (bf16_t*)(smem + 16384);   // 64 x 128 = 16 KB
    float* sj = (float*)(smem + 32768);
    float* dj = sj + 128;
    float* pj = dj + 128;

    int tid = threadIdx.x;
    if (tid < CHUNK) {
        sj[tid] = sarr[bc * CHUNK + tid];
        dj[tid] = dtv[bc * CHUNK + tid];
        pj[tid] = Pv[bc * CHUNK + tid];
    }
    int rowbase = bc * 128;
    int srow = tid >> 4;                     // 0..15
    int gsw  = (((tid & 15) ^ (srow & 7))) * 8;
    int lsl  = (tid & 15) * 8;
    #pragma unroll
    for (int i = 0; i < 4; ++i) {
        int row = srow + i * 16;             // 0..63 local
        load_lds16(&xbc[(size_t)(rowbase + bm * 64 + row) * NCONV + 1152 + gsw],
                   &Cs[row * 128 + lsl]);
        load_lds16(&xbc[(size_t)(rowbase + bn * 64 + row) * NCONV + 1024 + gsw],
                   &Bs2[row * 128 + lsl]);
    }
    __syncthreads();

    const int wave = tid >> 6, lane = tid & 63;
    const int lr = lane & 15, q = lane >> 4;
    const int wm = (wave & 1) * 32, wn = (wave >> 1) * 32;

    f32x4 acc[2][2];
    #pragma unroll
    for (int i = 0; i < 2; ++i)
        #pragma unroll
        for (int j = 0; j < 2; ++j)
            acc[i][j] = (f32x4){0.f, 0.f, 0.f, 0.f};

    #pragma unroll
    for (int k0 = 0; k0 < 128; k0 += 32) {
        bf16x8 af[2], bfr[2];
        #pragma unroll
        for (int mi = 0; mi < 2; ++mi) {
            int r = wm + mi * 16 + lr, kc = (k0 >> 3) + q;
            af[mi] = *reinterpret_cast<const bf16x8*>(
                &Cs[r * 128 + ((kc ^ (r & 7)) << 3)]);
        }
        #pragma unroll
        for (int ni = 0; ni < 2; ++ni) {
            int r = wn + ni * 16 + lr, kc = (k0 >> 3) + q;
            bfr[ni] = *reinterpret_cast<const bf16x8*>(
                &Bs2[r * 128 + ((kc ^ (r & 7)) << 3)]);
        }
        #pragma unroll
        for (int mi = 0; mi < 2; ++mi)
            #pragma unroll
            for (int ni = 0; ni < 2; ++ni)
                acc[mi][ni] = __builtin_amdgcn_mfma_f32_16x16x32_bf16(
                    af[mi], bfr[ni], acc[mi][ni], 0, 0, 0);
    }

    float A = -expf(A_log[0]);
    bf16_t* MxB = Mx + (size_t)bc * 32768;
    #pragma unroll
    for (int mi = 0; mi < 2; ++mi)
        #pragma unroll
        for (int ni = 0; ni < 2; ++ni)
            #pragma unroll
            for (int ri = 0; ri < 4; ++ri) {
                int row = bm * 64 + wm + mi * 16 + q * 4 + ri;
                int col = bn * 64 + wn + ni * 16 + lr;
                float val = 0.f;
                if (col <= row)
                    val = acc[mi][ni][ri] * expf(A * (sj[row] - sj[col])) * dj[col];
                MxB[(size_t)row * 256 + col] = (bf16_t)val;
            }

    // Cw half (bn==0 blocks own full C rows): Mx[row][128+n] = P_row * C[row][n]
    if (bn == 0) {
        int rl = tid >> 2;                   // 0..63 local row
        int cb2 = (tid & 3) * 32;            // 0,32,64,96
        float Pi = pj[bm * 64 + rl];
        #pragma unroll
        for (int m0 = 0; m0 < 32; m0 += 8) {
            int kc = (cb2 + m0) >> 3;
            bf16x8 cv = *reinterpret_cast<const bf16x8*>(
                &Cs[rl * 128 + ((kc ^ (rl & 7)) << 3)]);
            bf16x8 o;
            #pragma unroll
            for (int m = 0; m < 8; ++m) o[m] = (bf16_t)((float)cv[m] * Pi);
            *reinterpret_cast<bf16x8*>(
                &MxB[(size_t)(bm * 64 + rl) * 256 + 128 + cb2 + m0]) = o;
        }
    }
}

// ---------------------------------------------------------------------------
// scan_combine body: S_init(c) = chp*S_init + S_loc (prefetch-all).
// ---------------------------------------------------------------------------
__device__ __forceinline__ void scan_body(
    unsigned char* smem,
    const bf16_t* __restrict__ cstate, const float* __restrict__ chp,
    bf16_t* __restrict__ Stb, int blk)
{
    float* chS = (float*)smem;
    int idx = blk * 256 + threadIdx.x;   // B * 131072
    int b   = idx >> 17;
    int np  = idx & 131071;
    if (threadIdx.x < NCHUNK) chS[threadIdx.x] = chp[b * NCHUNK + threadIdx.x];
    __syncthreads();

    const bf16_t* src = cstate + ((size_t)b << 21) + np;
    bf16_t*       dst = Stb    + ((size_t)b << 21) + np;
    float t[NCHUNK];
    #pragma unroll
    for (int c = 0; c < NCHUNK; ++c) t[c] = (float)src[(size_t)c << 17];
    float v = 0.f;
    #pragma unroll
    for (int c = 0; c < NCHUNK; ++c) {
        dst[(size_t)c << 17] = (bf16_t)v;
        v = chS[c] * v + t[c];
    }
}

// Merged: mbuild64 (0..255) + scan_combine (256..2303) + ss-zero (2304..2335)
__global__ __launch_bounds__(256) void scan_mbuild_kernel(
    const bf16_t* __restrict__ cstate, const float* __restrict__ chp,
    bf16_t* __restrict__ Stb,
    const float* __restrict__ sarr, const float* __restrict__ dtv,
    const float* __restrict__ Pv, const float* __restrict__ A_log,
    const bf16_t* __restrict__ xbc, bf16_t* __restrict__ Mx,
    float* __restrict__ ss)
{
    __shared__ __align__(16) unsigned char smem[34304];
    int id = blockIdx.x;
    if (id < 256) {
        mbuild64_body(smem, sarr, dtv, Pv, A_log, xbc, Mx, id);
    } else if (id < 256 + BATCH * 131072 / 256) {
        scan_body(smem, cstate, chp, Stb, id - 256);
    } else {
        int i = (id - 256 - BATCH * 131072 / 256) * 256 + threadIdx.x;
        ss[i] = 0.f;                     // 32 blocks x 256 = 8192
    }
}

// ---------------------------------------------------------------------------
// Y-GEMM + fused gate: 64x64 tiles, 2048 blocks, chunk->XCD grouped.
// Y[i,p] = sum_{k<256} Mx[i,k]*Dx[p,k]; then epilogue: LDS acc transpose
// (16B-unit XOR swizzle), g=(y+D*x)*silu(z), write yb, atomic row sum(g^2).
// ---------------------------------------------------------------------------
__global__ __launch_bounds__(256) void gemm_y_kernel(
    const bf16_t* __restrict__ Mx, const bf16_t* __restrict__ Xt,
    const bf16_t* __restrict__ Stb, const bf16_t* __restrict__ zx,
    const bf16_t* __restrict__ xbc, const float* __restrict__ Dp,
    bf16_t* __restrict__ yb, float* __restrict__ ss)
{
    __shared__ __align__(16) bf16_t As[64 * 64];    //  8 KB
    __shared__ __align__(16) bf16_t Bs[64 * 64];    //  8 KB

    int id = blockIdx.x;                // [0,2048)
    int bc = id & 63;                   // chunk; XCD = bc & 7
    int t  = id >> 6;                   // [0,32)
    int half = t & 1, bn = t >> 1;      // row half [0,2), col tile [0,16)

    const bf16_t* Ab = Mx  + (size_t)bc * 32768 + (size_t)half * 64 * 256;   // 64x256
    const bf16_t* Xb = Xt  + (size_t)bc * 131072 + (size_t)bn * 64 * 128;
    const bf16_t* Sb = Stb + (size_t)bc * 131072 + (size_t)bn * 64 * 128;

    const int tid  = threadIdx.x;
    const int wave = tid >> 6, lane = tid & 63;
    const int lr = lane & 15, q = lane >> 4;
    const int wm = (wave & 1) * 32, wn = (wave >> 1) * 32;

    f32x4 acc[2][2];
    #pragma unroll
    for (int i = 0; i < 2; ++i)
        #pragma unroll
        for (int j = 0; j < 2; ++j)
            acc[i][j] = (f32x4){0.f, 0.f, 0.f, 0.f};

    const int srow = tid >> 3;
    const int gsw  = (((tid & 7) ^ (srow & 7))) * 8;
    const int lsl  = (tid & 7) * 8;

    for (int kt = 0; kt < 256; kt += 64) {
        const bf16_t* bsrc = (kt < 128) ? (Xb + kt) : (Sb + (kt - 128));
        #pragma unroll
        for (int i = 0; i < 2; ++i) {
            int row = srow + i * 32;
            load_lds16(&Ab[(size_t)row * 256 + kt + gsw], &As[row * 64 + lsl]);
            load_lds16(&bsrc[(size_t)row * 128 + gsw], &Bs[row * 64 + lsl]);
        }
        __syncthreads();
        #pragma unroll
        for (int k0 = 0; k0 < 64; k0 += 32) {
            bf16x8 af[2], bfr[2];
            #pragma unroll
            for (int mi = 0; mi < 2; ++mi) {
                int r = wm + mi * 16 + lr, kc = (k0 >> 3) + q;
                af[mi] = *reinterpret_cast<const bf16x8*>(
                    &As[r * 64 + ((kc ^ (r & 7)) << 3)]);
            }
            #pragma unroll
            for (int ni = 0; ni < 2; ++ni) {
                int r = wn + ni * 16 + lr, kc = (k0 >> 3) + q;
                bfr[ni] = *reinterpret_cast<const bf16x8*>(
                    &Bs[r * 64 + ((kc ^ (r & 7)) << 3)]);
            }
            #pragma unroll
            for (int mi = 0; mi < 2; ++mi)
                #pragma unroll
                for (int ni = 0; ni < 2; ++ni)
                    acc[mi][ni] = __builtin_amdgcn_mfma_f32_16x16x32_bf16(
                        af[mi], bfr[ni], acc[mi][ni], 0, 0, 0);
        }
        __syncthreads();
    }

    // ---- fused gate epilogue ----
    // Stage 64x64 acc tile into LDS (reuse As), swizzled at 16B-unit level:
    // unit(row,colgrp) = (row*8 + colgrp) ^ (row&7) -- conflict-free for the
    // scattered MFMA-layout writes AND the row-linear 16B reads.
    bf16_t* Yt = As;
    #pragma unroll
    for (int mi = 0; mi < 2; ++mi)
        #pragma unroll
        for (int ni = 0; ni < 2; ++ni)
            #pragma unroll
            for (int ri = 0; ri < 4; ++ri) {
                int row = wm + mi * 16 + q * 4 + ri;     // [0,64)
                int col = wn + ni * 16 + lr;             // [0,64)
                int u = (row * 8 + (col >> 3)) ^ (row & 7);
                Yt[u * 8 + (col & 7)] = (bf16_t)acc[mi][ni][ri];
            }
    __syncthreads();

    const int rr = tid >> 2, cq = tid & 3;               // row, col-quarter
    const size_t rg = (size_t)bc * 128 + half * 64 + rr; // global row
    const float D0 = Dp[0];
    float part = 0.f;
    #pragma unroll
    for (int j = 0; j < 2; ++j) {
        int u = (rr * 8 + cq * 2 + j) ^ (rr & 7);
        bf16x8 yv = *reinterpret_cast<const bf16x8*>(&Yt[u * 8]);
        int colg = bn * 64 + cq * 16 + j * 8;            // [0,1024)
        bf16x8 zv = *reinterpret_cast<const bf16x8*>(zx  + rg * NZX   + colg);
        bf16x8 xv = *reinterpret_cast<const bf16x8*>(xbc + rg * NCONV + colg);
        bf16x8 o;
        #pragma unroll
        for (int m = 0; m < 8; ++m) {
            float g = ((float)yv[m] + D0 * (float)xv[m]) * siluf((float)zv[m]);
            part += g * g;
            o[m] = (bf16_t)g;
        }
        *reinterpret_cast<bf16x8*>(yb + rg * DINNER + colg) = o;
    }
    part += __shfl_xor(part, 1);
    part += __shfl_xor(part, 2);
    if ((tid & 3) == 0) atomicAdd(&ss[rg], part);
}

// ---------------------------------------------------------------------------
// Fused: dt column + x->bf16 cast [blocks 0..2047], then W_in cast /
// W_out*norm_w cast / rnn passthrough tails.
// ---------------------------------------------------------------------------
__global__ __launch_bounds__(256) void dtcast_kernel(
    const float* __restrict__ x, const float* __restrict__ W_in,
    const float* __restrict__ dt_bias, const float* __restrict__ W_out,
    const float* __restrict__ norm_w, const float* __restrict__ rnn,
    float* __restrict__ dtv, bf16_t* __restrict__ xb,
    bf16_t* __restrict__ winb, bf16_t* __restrict__ woutb,
    float* __restrict__ outTail)
{
    int bid = blockIdx.x;
    if (bid < MROWS / 4) {
        int wave = threadIdx.x >> 6, lane = threadIdx.x & 63;
        int r = bid * 4 + wave;
        const float* xr = x + (size_t)r * DMODEL + lane * 8;
        const float* wr = W_in + (size_t)NZX * DMODEL + lane * 8;
        float4 a0 = *reinterpret_cast<const float4*>(xr);
        float4 a1 = *reinterpret_cast<const float4*>(xr + 4);
        float4 b0 = *reinterpret_cast<const float4*>(wr);
        float4 b1 = *reinterpret_cast<const float4*>(wr + 4);

        bf16x8 xo;
        xo[0] = (bf16_t)a0.x; xo[1] = (bf16_t)a0.y; xo[2] = (bf16_t)a0.z; xo[3] = (bf16_t)a0.w;
        xo[4] = (bf16_t)a1.x; xo[5] = (bf16_t)a1.y; xo[6] = (bf16_t)a1.z; xo[7] = (bf16_t)a1.w;
        *reinterpret_cast<bf16x8*>(xb + (size_t)r * DMODEL + lane * 8) = xo;

        float s = a0.x * b0.x + a0.y * b0.y + a0.z * b0.z + a0.w * b0.w
                + a1.x * b1.x + a1.y * b1.y + a1.z * b1.z + a1.w * b1.w;
        #pragma unroll
        for (int m = 32; m >= 1; m >>= 1) s += __shfl_xor(s, m);
        if (lane == 0) {
            float t  = s + dt_bias[0];
            dtv[r] = (t > 20.f) ? t : log1pf(expf(t));
        }
        return;
    }
    int i = (bid - MROWS / 4) * 256 + threadIdx.x;
    const int n4a = 2305 * DMODEL / 4, n4b = DMODEL * DINNER / 4;
    if (i < n4a) {
        float4 v = reinterpret_cast<const float4*>(W_in)[i];
        bf16x4 o;
        o[0] = (bf16_t)v.x; o[1] = (bf16_t)v.y; o[2] = (bf16_t)v.z; o[3] = (bf16_t)v.w;
        reinterpret_cast<bf16x4*>(winb)[i] = o;
    } else if (i < n4a + n4b) {
        int j = i - n4a;
        float4 v = reinterpret_cast<const float4*>(W_out)[j];
        int c0 = (j * 4) & (DINNER - 1);
        float4 w = *reinterpret_cast<const float4*>(norm_w + c0);
        bf16x4 o;
        o[0] = (bf16_t)(v.x * w.x); o[1] = (bf16_t)(v.y * w.y);
        o[2] = (bf16_t)(v.z * w.z); o[3] = (bf16_t)(v.w * w.w);
        reinterpret_cast<bf16x4*>(woutb)[j] = o;
    } else if (i < n4a + n4b + BATCH * DMODEL) {
        int k = i - n4a - n4b;
        outTail[k] = rnn[k];
    }
}

// ---------------------------------------------------------------------------
// Fused conv + transpose (R11 layout): 1280 blocks, 128x64 tile, TS=66.
// ---------------------------------------------------------------------------
__global__ __launch_bounds__(256) void conv_tr_kernel(
    const bf16_t* __restrict__ zx, const float* __restrict__ cw,
    const float* __restrict__ cb, const float* __restrict__ EdTv,
    bf16_t* __restrict__ xbc, bf16_t* __restrict__ Xt, bf16_t* __restrict__ Bwt)
{
    constexpr int TS = 66;                 // 132B row stride = 33 banks (odd)
    __shared__ bf16_t tile[128 * TS];      // [j][ch_local]
    __shared__ float cwS[64 * 4];
    __shared__ float cbS[64];

    int id  = blockIdx.x;                  // [0,1280)
    int xcd = id & 7;
    int k   = id >> 3;                     // [0,160)
    int bc  = xcd * 8 + (k & 7);           // zx band bc lives in XCD bc>>3 L2
    int rest = k >> 3;                     // [0,20)
    int cg   = rest >> 1;                  // [0,10)
    int half = rest & 1;
    int c0   = cg * 128 + half * 64;       // global channel base in [0,1280)
    int tid  = threadIdx.x;

    if (tid < 64) {
        float4 w = *reinterpret_cast<const float4*>(cw + (size_t)(c0 + tid) * 4);
        *reinterpret_cast<float4*>(&cwS[tid * 4]) = w;
        cbS[tid] = cb[c0 + tid];
    }
    __syncthreads();

    int lrow = tid >> 3;                   // 0..31
    int lc8  = (tid & 7) * 8;              // 0..56 (channel-local)
    int g0 = bc * 128;

    #pragma unroll
    for (int pass = 0; pass < 4; ++pass) {
        int row = pass * 32 + lrow;        // j in chunk
        int g = g0 + row;
        int l = g & (SEQLEN - 1);
        float acc[8];
        #pragma unroll
        for (int m = 0; m < 8; ++m) acc[m] = cbS[lc8 + m];
        #pragma unroll
        for (int kk = 0; kk < 4; ++kk) {
            if (l + kk >= 3) {
                bf16x8 v = *reinterpret_cast<const bf16x8*>(
                    zx + (size_t)(g + kk - 3) * NZX + DINNER + c0 + lc8);
                #pragma unroll
                for (int m = 0; m < 8; ++m)
                    acc[m] += cwS[(lc8 + m) * 4 + kk] * (float)v[m];
            }
        }
        bf16x8 o;
        #pragma unroll
        for (int m = 0; m < 8; ++m) o[m] = (bf16_t)siluf(acc[m]);
        *reinterpret_cast<bf16x8*>(xbc + (size_t)g * NCONV + c0 + lc8) = o;
        if (cg < 9) {
            #pragma unroll
            for (int jj = 0; jj < 4; ++jj) {
                bf16x2 p; p[0] = o[jj * 2]; p[1] = o[jj * 2 + 1];
                *reinterpret_cast<bf16x2*>(&tile[row * TS + lc8 + jj * 2]) = p;
            }
        }
    }
    if (cg == 9) return;
    __syncthreads();

    const bool isB = (cg == 8);
    int jo = (tid >> 4) * 8;               // j-block 0..120
    int i  = tid & 15;
    float sc[8];
    #pragma unroll
    for (int m = 0; m < 8; ++m)
        sc[m] = isB ? EdTv[bc * 128 + jo + m] : 1.f;

    #pragma unroll
    for (int pass = 0; pass < 4; ++pass) {
        int oc = pass * 16 + i;            // channel-local 0..63
        bf16x8 o;
        #pragma unroll
        for (int m = 0; m < 8; ++m)
            o[m] = (bf16_t)((float)tile[(jo + m) * TS + oc] * sc[m]);
        bf16_t* dst = isB
            ? (Bwt + (size_t)bc * 16384 + (size_t)(c0 - 1024 + oc) * 128 + jo)
            : (Xt + (size_t)bc * 131072 + (size_t)(c0 + oc) * 128 + jo);
        *reinterpret_cast<bf16x8*>(dst) = o;
    }
}

// ---------------------------------------------------------------------------
extern "C" void kernel_launch(void* const* d_in, const int* in_sizes, int n_in,
                              void* d_out, int out_size, void* d_ws, size_t ws_size,
                              hipStream_t stream)
{
    const float* x        = (const float*)d_in[0];
    const float* rnn      = (const float*)d_in[1];
    const float* W_in     = (const float*)d_in[2];
    const float* conv_w   = (const float*)d_in[3];
    const float* conv_b   = (const float*)d_in[4];
    const float* dt_bias  = (const float*)d_in[5];
    const float* A_log    = (const float*)d_in[6];
    const float* Dp       = (const float*)d_in[7];
    const float* norm_w   = (const float*)d_in[8];
    const float* W_out    = (const float*)d_in[9];
    float* out = (float*)d_out;

    // workspace carve
    char* ws = (char*)d_ws;
    bf16_t* xb     = (bf16_t*)(ws + 0);                       //  8,388,608 (dead after GEMM1)
    float*  ssn    = (float*) (ws + 0);                       //     32,768 (alias over dead xb head)
    bf16_t* Mx     = (bf16_t*)(ws + 4194304);                 //  4,194,304 (alias over xb tail)
    bf16_t* winb   = (bf16_t*)(ws + 8388608);                 //  2,360,320
    bf16_t* woutb  = (bf16_t*)(ws + 10748928);                //  1,048,576
    bf16_t* zx     = (bf16_t*)(ws + 11797504);                // 37,748,736
    float*  dtv    = (float*) (ws + 49546240);                //     32,768
    float*  sarr   = (float*) (ws + 49579008);                //     32,768
    float*  Pv     = (float*) (ws + 49611776);                //     32,768
    float*  EdTv   = (float*) (ws + 49644544);                //     32,768
    float*  chp    = (float*) (ws + 49677312);                //        256
    bf16_t* xbcb   = (bf16_t*)(ws + 49677568);                // 20,971,520
    bf16_t* Xt     = (bf16_t*)(ws + 70649088);                // 16,777,216
    bf16_t* Bwt    = (bf16_t*)(ws + 87426304);                //  2,097,152
    bf16_t* cstate = (bf16_t*)(ws + 89523456);                // 16,777,216 (S_loc bf16)
    bf16_t* Stb    = (bf16_t*)(ws + 106300672);               // 16,777,216
    bf16_t* yb     = (bf16_t*)(ws + 123077888);               // 16,777,216
    // end: 139,855,104 bytes

    // 1) dt (fp32) + x cast + weight casts (+norm_w fold) + rnn passthrough
    {
        const int n4a = 2305 * DMODEL / 4, n4b = DMODEL * DINNER / 4;
        int nrest = n4a + n4b + BATCH * DMODEL;
        int grid = MROWS / 4 + (nrest + 255) / 256;
        dtcast_kernel<<<grid, 256, 0, stream>>>(
            x, W_in, dt_bias, W_out, norm_w, rnn, dtv, xb, winb, woutb,
            out + (size_t)MROWS * DMODEL);
    }

    // 2) GEMM1 (64x128 tiles, 2304 blocks + fused cumsum tail blocks)
    gemm1_kernel<<<2304 + NBC, 256, 0, stream>>>(
        xb, winb, zx, dtv, A_log, sarr, Pv, EdTv, chp);

    // 3) fused conv + transpose (1280 blocks, XCD-matched to zx bands)
    conv_tr_kernel<<<1280, 256, 0, stream>>>(
        zx, conv_w, conv_b, EdTv, xbcb, Xt, Bwt);

    // 4) GEMM-A standalone: 64x64 tiles, 2048 blocks, 16 KB LDS
    gemmA_kernel<<<2048, 256, 0, stream>>>(Xt, Bwt, cstate);

    // 5) mbuild64 (256) + combine -> Stb (2048) + ss-zero (32), merged
    scan_mbuild_kernel<<<256 + BATCH * 131072 / 256 + 32, 256, 0, stream>>>(
        cstate, chp, Stb, sarr, dtv, Pv, A_log, xbcb, Mx, ssn);

    // 6) GEMM-Y + fused gate: yb = g bf16, ss += row sums
    gemm_y_kernel<<<2048, 256, 0, stream>>>(
        Mx, Xt, Stb, zx, xbcb, Dp, yb, ssn);

    // 7) GEMM2 (+RMSNorm scale epilogue, norm_w pre-folded into woutb)
    gemm2_kernel<<<1024, 256, 0, stream>>>(yb, woutb, ssn, out);
}